// Round 1
// baseline (14966.896 us; speedup 1.0000x reference)
//
#include <hip/hip_runtime.h>
#include <stdint.h>

// BetterMCMC R11: attack the LDS pipe + barrier structure of the 1-CU serial chain.
//  - Speculative dual-branch prefetch of next step's rows/scalars (accept AND reject
//    variants known after argmax) -> B2 and the serial L3 row latency are gone.
//  - All wave reductions via DPP (VALU) instead of __shfl_down (ds_bpermute);
//    cross-wave finalize via one conflict-free lane-indexed read + 16-lane DPP
//    butterfly -> every lane gets the result (replaces 2x 16-iteration broadcast loops).
//  - Accept decision computed redundantly by all threads (all inputs uniform,
//    w_cur register-replicated) -> B7 + tid0 serial section gone. 3 barriers/step.
//  - Strided element mapping (i = tid + k*1024) -> perm/pairw LDS reads conflict-free;
//    gumbel table stored pre-transposed so the per-step gumbel stays one float4.
// Numerics: per-element formulas bit-identical to R10. Argmax exact under any order.
// f64 pair-sum only reordered (DPP tree vs shfl tree): ~1e-13 rel shift, far below
// the 2e-4 decision margin already survived.

#define NW 4096
#define NSTEPS 2559
#define NTHREADS 1024
#define NWAVES 16

typedef unsigned long long u64;
typedef uint32_t u32;
typedef unsigned short u16;

__device__ __forceinline__ u32 rotl32(u32 v, u32 r) { return (v << r) | (v >> (32u - r)); }

// Threefry-2x32, 20 rounds, exactly as jax/_src/prng.py threefry2x32.
__device__ __forceinline__ void tf2x32(u32 k0, u32 k1, u32 x0, u32 x1, u32* o0, u32* o1) {
  u32 ks2 = k0 ^ k1 ^ 0x1BD11BDAu;
  x0 += k0; x1 += k1;
#define TFR(r0, r1, r2, r3)                      \
  x0 += x1; x1 = rotl32(x1, r0); x1 ^= x0;       \
  x0 += x1; x1 = rotl32(x1, r1); x1 ^= x0;       \
  x0 += x1; x1 = rotl32(x1, r2); x1 ^= x0;       \
  x0 += x1; x1 = rotl32(x1, r3); x1 ^= x0;
  TFR(13, 15, 26, 6)  x0 += k1;  x1 += ks2 + 1u;
  TFR(17, 29, 16, 24) x0 += ks2; x1 += k0 + 2u;
  TFR(13, 15, 26, 6)  x0 += k0;  x1 += k1 + 3u;
  TFR(17, 29, 16, 24) x0 += k1;  x1 += ks2 + 4u;
  TFR(13, 15, 26, 6)  x0 += ks2; x1 += k0 + 5u;
#undef TFR
  *o0 = x0; *o1 = x1;
}

__device__ __forceinline__ float unif01(u32 bits) {
  return __uint_as_float((bits >> 9) | 0x3f800000u) - 1.0f;
}

__device__ __forceinline__ u32 fkey(float f) {
  u32 b = __float_as_uint(f);
  return b ^ ((b >> 31) ? 0xFFFFFFFFu : 0x80000000u);
}

// ---------------- DPP reduction helpers (VALU, no LDS pipe) ----------------
// ctrl encodings: ROW_SHR|n = 0x110|n, ROW_BCAST15 = 0x142, ROW_BCAST31 = 0x143,
// quad_perm xor1 = 0xB1, xor2 = 0x4E, ROW_HALF_MIRROR = 0x141, ROW_MIRROR = 0x140.

template <int CTRL>
__device__ __forceinline__ u32 dpp32(u32 v) {
  return (u32)__builtin_amdgcn_update_dpp(0, (int)v, CTRL, 0xF, 0xF, true);
}

template <int CTRL>
__device__ __forceinline__ void dppmax64(u32& hi, u32& lo) {
  u32 h2 = dpp32<CTRL>(hi);
  u32 l2 = dpp32<CTRL>(lo);
  bool g = (h2 > hi) || (h2 == hi && l2 > lo);
  hi = g ? h2 : hi;
  lo = g ? l2 : lo;
}

template <int CTRL>
__device__ __forceinline__ double dppadd64(double d) {
  u32 lo = (u32)__double2loint(d);
  u32 hi = (u32)__double2hiint(d);
  u32 l2 = dpp32<CTRL>(lo);
  u32 h2 = dpp32<CTRL>(hi);
  return d + __hiloint2double((int)h2, (int)l2);
}

// wave64 reduce; result valid in lane 63 (zero-fill: key 0 never wins; +0.0 is identity)
__device__ __forceinline__ u64 wave_max_u64(u64 key) {
  u32 lo = (u32)key, hi = (u32)(key >> 32);
  dppmax64<0x111>(hi, lo); dppmax64<0x112>(hi, lo);
  dppmax64<0x114>(hi, lo); dppmax64<0x118>(hi, lo);
  dppmax64<0x142>(hi, lo); dppmax64<0x143>(hi, lo);
  return ((u64)hi << 32) | lo;
}

__device__ __forceinline__ double wave_sum_f64(double d) {
  d = dppadd64<0x111>(d); d = dppadd64<0x112>(d);
  d = dppadd64<0x114>(d); d = dppadd64<0x118>(d);
  d = dppadd64<0x142>(d); d = dppadd64<0x143>(d);
  return d;  // lane 63
}

// 16-lane butterfly (xor1, xor2, mirror8, mirror16) -> ALL lanes hold the result
__device__ __forceinline__ u64 bfly16_max_u64(u64 key) {
  u32 lo = (u32)key, hi = (u32)(key >> 32);
  dppmax64<0xB1>(hi, lo); dppmax64<0x4E>(hi, lo);
  dppmax64<0x141>(hi, lo); dppmax64<0x140>(hi, lo);
  return ((u64)hi << 32) | lo;
}

__device__ __forceinline__ double bfly16_sum_f64(double d) {
  d = dppadd64<0xB1>(d); d = dppadd64<0x4E>(d);
  d = dppadd64<0x141>(d); d = dppadd64<0x140>(d);
  return d;  // all lanes identical (IEEE add commutativity => lane-wise bit-identical)
}

// ---------------- prep kernels (massively parallel) ----------------

#define TT 32
__global__ void transpose_k(const float* __restrict__ in, float* __restrict__ out) {
  __shared__ float tile[TT][TT + 1];
  int x = blockIdx.x * TT + threadIdx.x;
  int y = blockIdx.y * TT + threadIdx.y;
  for (int j = 0; j < TT; j += 8) tile[threadIdx.y + j][threadIdx.x] = in[(u64)(y + j) * NW + x];
  __syncthreads();
  x = blockIdx.y * TT + threadIdx.x;
  y = blockIdx.x * TT + threadIdx.y;
  for (int j = 0; j < TT; j += 8) out[(u64)(y + j) * NW + x] = tile[threadIdx.x][threadIdx.y + j];
}

// Stores pre-transposed within each step-row: slot p holds gumbel of element
// i = (p>>2) | ((p&3)<<10), so main-kernel thread tid float4-loads elements
// {tid, tid+1024, tid+2048, tid+3072}. Store remains fully coalesced.
__global__ void gumbel_k(float* __restrict__ gumb) {
  long long idx = (long long)blockIdx.x * blockDim.x + threadIdx.x;
  if (idx >= (long long)NSTEPS * NW) return;
  int t = (int)(idx >> 12);
  int p = (int)(idx & (NW - 1));
  int i = (p >> 2) | ((p & 3) << 10);
  u32 kt0, kt1, kc0, kc1, ba, bb;
  tf2x32(0u, 42u, 0u, (u32)t, &kt0, &kt1);         // keys[t]
  tf2x32(kt0, kt1, 0u, 1u, &kc0, &kc1);            // k_cat = split(keys[t],3)[1]
  tf2x32(kc0, kc1, 0u, (u32)i, &ba, &bb);
  float u = unif01(ba ^ bb);                       // bits = w1 ^ w2
  if (u == 0.0f) u = 1.17549435e-38f;
  float t1 = (float)log((double)u);
  float t2 = (float)log((double)(-t1));
  gumb[idx] = -t2;
}

__global__ void posu_k(int* __restrict__ posArr, float* __restrict__ uArr) {
  int t = blockIdx.x * blockDim.x + threadIdx.x;
  if (t >= NSTEPS) return;
  u32 kt0, kt1, kp0, kp1, ku0, ku1, k2a, k2b, ra, rb, ua, ub;
  tf2x32(0u, 42u, 0u, (u32)t, &kt0, &kt1);         // keys[t]
  tf2x32(kt0, kt1, 0u, 0u, &kp0, &kp1);            // k_pos
  tf2x32(kt0, kt1, 0u, 2u, &ku0, &ku1);            // k_u
  tf2x32(kp0, kp1, 0u, 1u, &k2a, &k2b);            // k2 = split(k_pos)[1]
  tf2x32(k2a, k2b, 0u, 0u, &ra, &rb);
  posArr[t] = (int)((ra ^ rb) & (u32)(NW - 1));    // bits = w1 ^ w2
  tf2x32(ku0, ku1, 0u, 0u, &ua, &ub);
  uArr[t] = unif01(ua ^ ub);
}

// ---------------- main chain kernel ----------------

// proposed sample element at index idx (reads pre-commit s_perm; uses np/pos/tm)
#define SAMPLE_AT(idx)                                                        \
  ((idx) < np ? (int)s_perm[(idx) + ((idx) >= pos)]                           \
              : ((idx) == np ? tm                                             \
                             : (int)s_perm[((idx)-1) + (((idx)-1) >= pos)]))

__global__ __launch_bounds__(NTHREADS)
void mcmc_fast9(const float* __restrict__ bigram,
                const float* __restrict__ bigT,
                const float* __restrict__ gumb,
                const int* __restrict__ posArr,
                const float* __restrict__ uArr,
                const float* __restrict__ startv,
                const float* __restrict__ endv,
                int* __restrict__ out) {
  __shared__ u16    s_perm[NW];       // 8 KB
  __shared__ float  s_pairw[NW];      // 16 KB  current perm pair values
  __shared__ float  s_rowB[NW];       // 16 KB  bigram[tm, :]
  __shared__ float  s_rowT[NW];       // 16 KB  bigram[:, tm]
  __shared__ u64    s_redu[NWAVES];   // argmax partials
  __shared__ double s_redd2[NWAVES];  // pair-sum partials
  __shared__ float  s_stm, s_etm, s_bridge;

  const int tid = threadIdx.x;
  const int lane = tid & 63;
  const int wid = tid >> 6;

  // ---- init: identity perm; pairw = bigram[j, j+1]; stage step-0 rows ----
  for (int i = tid; i < NW; i += NTHREADS) s_perm[i] = (u16)i;
  for (int j = tid; j < NW - 1; j += NTHREADS) s_pairw[j] = bigram[(u64)j * NW + (j + 1)];

  int pos = posArr[0];
  float u_cur = uArr[0];
  int tm = pos;                       // identity perm: perm[pos] == pos
  {
    float4 rb4 = ((const float4*)(bigram + (u64)tm * NW))[tid];
    float4 rt4 = ((const float4*)(bigT + (u64)tm * NW))[tid];
    ((float4*)s_rowB)[tid] = rb4;
    ((float4*)s_rowT)[tid] = rt4;
  }
  if (tid == 0) { s_stm = startv[tm]; s_etm = endv[tm]; s_bridge = 0.0f; }
  if (tid == 1 && pos >= 1 && pos <= NW - 2)
    s_bridge = bigram[(u64)(pos - 1) * NW + (pos + 1)];   // identity-perm bridge
  __syncthreads();

  float w_cur;
  {
    double ds = 0.0;
#pragma unroll
    for (int k = 0; k < 4; ++k) {
      int j = tid + k * NTHREADS;
      ds += (j < NW - 1) ? (double)s_pairw[j] : 0.0;
    }
    ds = wave_sum_f64(ds);
    if (lane == 63) s_redd2[wid] = ds;
    __syncthreads();
    double d = bfly16_sum_f64(s_redd2[lane & 15]);
    float S = (float)d;
    S = S + startv[0];
    S = S + endv[NW - 1];
    w_cur = S;                        // replicated in every thread
  }
  float4 g4 = ((const float4*)gumb)[tid];

  for (int t = 0; t < NSTEPS; ++t) {
    // ---- Phase A: logits + gumbel argmax (strided i = tid + k*1024) ----
    const float gg[4] = {g4.x, g4.y, g4.z, g4.w};
    int pos_nxt; float u_nxt;
    {
      int tn = (t + 1 < NSTEPS) ? (t + 1) : (NSTEPS - 1);
      g4 = ((const float4*)(gumb + ((u64)tn << 12)))[tid];   // for step t+1
      pos_nxt = posArr[tn];
      u_nxt = uArr[tn];
    }
    u64 best = 0;
#pragma unroll
    for (int k = 0; k < 4; ++k) {
      int i = tid + k * NTHREADS;
      float li;
      if (i == 0) {
        int r = s_perm[(0 >= pos) ? 1 : 0];
        li = s_stm + s_rowB[r];
      } else if (i == NW - 1) {
        int l = s_perm[((NW - 2) >= pos) ? (NW - 1) : (NW - 2)];
        li = s_etm + s_rowT[l];
      } else {
        int l = s_perm[(i - 1) + ((i - 1) >= pos)];
        int r = s_perm[i + (i >= pos)];
        li = s_rowT[l] + s_rowB[r];                  // fl(left + right), same bits as R10
      }
      float sv = gg[k] + li;
      u64 key = ((u64)fkey(sv) << 32) | (u32)(NW - 1 - i);
      if (key > best) best = key;
    }
    best = wave_max_u64(best);
    if (lane == 63) s_redu[wid] = best;
    __syncthreads();                                                  // B3

    // ---- Phase B: finalize argmax; specials; speculation for t+1; pair sum ----
    int np;
    {
      u64 bb = bfly16_max_u64(s_redu[lane & 15]);   // conflict-free, all lanes
      np = NW - 1 - (int)(bb & 0xFFFFFFFFu);
    }
    float vnpm1 = 0.0f, vnp = 0.0f;
    if (np >= 1)      vnpm1 = s_rowT[s_perm[(np - 1) + ((np - 1) >= pos)]];
    if (np <= NW - 2) vnp   = s_rowB[s_perm[np + (np >= pos)]];
    float lnp, lpos;
    {
      int idx2[2] = {np, pos};
      float o2[2];
#pragma unroll
      for (int q = 0; q < 2; ++q) {
        int i = idx2[q];
        float li;
        if (i == 0) {
          int r = s_perm[(0 >= pos) ? 1 : 0];
          li = s_stm + s_rowB[r];
        } else if (i == NW - 1) {
          int l = s_perm[((NW - 2) >= pos) ? (NW - 1) : (NW - 2)];
          li = s_etm + s_rowT[l];
        } else {
          int l = s_perm[(i - 1) + ((i - 1) >= pos)];
          int r = s_perm[i + (i >= pos)];
          li = s_rowT[l] + s_rowB[r];
        }
        o2[q] = li;
      }
      lnp = o2[0]; lpos = o2[1];
    }
    int s0 = (0 < np) ? (int)s_perm[(0 >= pos) ? 1 : 0] : tm;
    int sl = ((NW - 1) == np) ? tm : (int)s_perm[(NW - 2) + ((NW - 2) >= pos)];
    float a0 = startv[s0];
    float a1 = endv[sl];

    // speculative prefetch of BOTH branches of step t+1 (tm under accept/reject)
    const int tmR = (int)s_perm[pos_nxt];
    const int tmA = SAMPLE_AT(pos_nxt);
    float4 rbA = ((const float4*)(bigram + (u64)tmA * NW))[tid];
    float4 rtA = ((const float4*)(bigT + (u64)tmA * NW))[tid];
    float4 rbR = ((const float4*)(bigram + (u64)tmR * NW))[tid];
    float4 rtR = ((const float4*)(bigT + (u64)tmR * NW))[tid];
    float stmA = 0.0f, etmA = 0.0f, stmR = 0.0f, etmR = 0.0f, brA = 0.0f, brR = 0.0f;
    if (tid == 0) {
      stmA = startv[tmA]; etmA = endv[tmA];
      stmR = startv[tmR]; etmR = endv[tmR];
    }
    const bool brg = (pos_nxt >= 1 && pos_nxt <= NW - 2);
    if (tid == 1 && brg) {
      brR = bigram[(u64)s_perm[pos_nxt - 1] * NW + s_perm[pos_nxt + 1]];
      int la = SAMPLE_AT(pos_nxt - 1);
      int ra = SAMPLE_AT(pos_nxt + 1);
      brA = bigram[(u64)la * NW + ra];
    }

    // sample pair values + sample perm (strided j = tid + k*1024; conflict-free)
    const float brv = s_bridge;
    float newp[4];
    u16 stash[4];
#pragma unroll
    for (int k = 0; k < 4; ++k) {
      int j = tid + k * NTHREADS;
      float v = 0.0f;
      if (j < NW - 1) {
        int kk = (j < np) ? j : (j - 1);
        float pw = s_pairw[(kk < pos - 1) ? kk : (kk + 1)];   // single read; sel below
        pw = (kk == pos - 1) ? brv : pw;
        v = (j == np - 1) ? vnpm1 : ((j == np) ? vnp : pw);
      }
      newp[k] = v;
      stash[k] = (j < np) ? s_perm[j + (j >= pos)]
                          : ((j == np) ? (u16)tm : s_perm[(j - 1) + ((j - 1) >= pos)]);
    }
    {
      double ds = (((double)newp[0] + (double)newp[1]) + (double)newp[2]) + (double)newp[3];
      ds = wave_sum_f64(ds);
      if (lane == 63) s_redd2[wid] = ds;
    }
    __syncthreads();                                                  // B6

    // ---- Phase C: redundant accept on all threads; commit selected state ----
    {
      double d = bfly16_sum_f64(s_redd2[lane & 15]);
      float S = (float)d;
      S = S + a0;
      S = S + a1;
      float dw = S - w_cur;
      double ed = (double)dw + ((double)lnp - (double)lpos);
      float a = (float)exp(ed);
      a = fminf(1.0f, a);
      const bool acc = (a > u_cur);
      if (acc) {
        w_cur = S;
#pragma unroll
        for (int k = 0; k < 4; ++k) {
          int j = tid + k * NTHREADS;
          s_perm[j] = stash[k];
          if (j < NW - 1) s_pairw[j] = newp[k];
        }
      }
      ((float4*)s_rowB)[tid] = acc ? rbA : rbR;
      ((float4*)s_rowT)[tid] = acc ? rtA : rtR;
      if (tid == 0) { s_stm = acc ? stmA : stmR; s_etm = acc ? etmA : etmR; }
      if (tid == 1 && brg) s_bridge = acc ? brA : brR;
      tm = acc ? tmA : tmR;
      pos = pos_nxt;
      u_cur = u_nxt;
    }
    __syncthreads();                                                  // B9

    // ---- emit thinned sample ----
    if ((t % 10) == 8) {
      int row = (t - 8) / 10;
      ushort4 p4 = ((const ushort4*)s_perm)[tid];
      int4 o4;
      o4.x = (int)p4.x; o4.y = (int)p4.y; o4.z = (int)p4.z; o4.w = (int)p4.w;
      ((int4*)(out + (u64)row * NW))[tid] = o4;
    }
  }
}

// ---------------- fallback (R2 kernel, verified) ----------------

__global__ __launch_bounds__(NTHREADS)
void mcmc_kernel(const float* __restrict__ bigram,
                 const float* __restrict__ startv,
                 const float* __restrict__ endv,
                 int* __restrict__ out) {
  __shared__ int    s_perm[NW];
  __shared__ float  s_logit[NW];
  __shared__ float  s_gath[NW];
  __shared__ float  s_redf[NWAVES];
  __shared__ u64    s_redu[NWAVES];
  __shared__ double s_redd[NWAVES];
  __shared__ float  s_m, s_Z, s_w;
  __shared__ int    s_pos, s_tm, s_np, s_acc;
  __shared__ u32    s_kcat0, s_kcat1, s_ku0, s_ku1;

  const int tid = threadIdx.x;
  const int lane = tid & 63;
  const int wid = tid >> 6;

  for (int i = tid; i < NW; i += NTHREADS) s_perm[i] = i;
  for (int j = tid; j < NW - 1; j += NTHREADS) s_gath[j] = bigram[(u64)j * NW + (j + 1)];
  __syncthreads();
  if (tid == 0) {
    float S = 0.0f;
    for (int j = 0; j < NW - 1; ++j) S += s_gath[j];
    S = S + startv[0];
    S = S + endv[NW - 1];
    s_w = S;
  }
  __syncthreads();

  for (int t = 0; t < NSTEPS; ++t) {
    if (tid == 0) {
      u32 kt0, kt1;
      tf2x32(0u, 42u, 0u, (u32)t, &kt0, &kt1);
      u32 kp0, kp1, kc0, kc1, ku0, ku1;
      tf2x32(kt0, kt1, 0u, 0u, &kp0, &kp1);
      tf2x32(kt0, kt1, 0u, 1u, &kc0, &kc1);
      tf2x32(kt0, kt1, 0u, 2u, &ku0, &ku1);
      u32 k2a, k2b, ra, rb;
      tf2x32(kp0, kp1, 0u, 1u, &k2a, &k2b);
      tf2x32(k2a, k2b, 0u, 0u, &ra, &rb);
      int pos = (int)((ra ^ rb) & (u32)(NW - 1));
      s_pos = pos;
      s_tm = s_perm[pos];
      s_kcat0 = kc0; s_kcat1 = kc1; s_ku0 = ku0; s_ku1 = ku1;
    }
    __syncthreads();
    const int pos = s_pos, tm = s_tm;

    float lmax = -3.402823466e+38f;
    for (int i = tid; i < NW; i += NTHREADS) {
      float li;
      if (i == 0) {
        int r = s_perm[(0 >= pos) ? 1 : 0];
        li = startv[tm] + bigram[(u64)tm * NW + r];
      } else if (i == NW - 1) {
        int l = s_perm[((NW - 2) >= pos) ? (NW - 1) : (NW - 2)];
        li = endv[tm] + bigram[(u64)l * NW + tm];
      } else {
        int l = s_perm[((i - 1) >= pos) ? i : (i - 1)];
        int r = s_perm[(i >= pos) ? (i + 1) : i];
        li = bigram[(u64)l * NW + tm] + bigram[(u64)tm * NW + r];
      }
      s_logit[i] = li;
      lmax = fmaxf(lmax, li);
    }
    for (int o = 32; o > 0; o >>= 1) lmax = fmaxf(lmax, __shfl_down(lmax, o, 64));
    if (lane == 0) s_redf[wid] = lmax;
    __syncthreads();
    if (tid == 0) {
      float m = s_redf[0];
      for (int w = 1; w < NWAVES; ++w) m = fmaxf(m, s_redf[w]);
      s_m = m;
    }
    __syncthreads();
    const float m = s_m;

    double zacc = 0.0;
    u64 best = 0;
    const u32 kc0 = s_kcat0, kc1 = s_kcat1;
    for (int i = tid; i < NW; i += NTHREADS) {
      float li = s_logit[i];
      float ex = (float)exp((double)(li - m));
      zacc += (double)ex;
      u32 ba, bb;
      tf2x32(kc0, kc1, 0u, (u32)i, &ba, &bb);
      float u = unif01(ba ^ bb);
      if (u == 0.0f) u = 1.17549435e-38f;
      float t1 = (float)log((double)u);
      float t2 = (float)log((double)(-t1));
      float g = -t2;
      float sv = g + li;
      u64 key = ((u64)fkey(sv) << 32) | (u32)(NW - 1 - i);
      if (key > best) best = key;
    }
    for (int o = 32; o > 0; o >>= 1) {
      u64 w = __shfl_down(best, o, 64);
      if (w > best) best = w;
      zacc += __shfl_down(zacc, o, 64);
    }
    if (lane == 0) { s_redu[wid] = best; s_redd[wid] = zacc; }
    __syncthreads();
    if (tid == 0) {
      u64 b = s_redu[0]; double z = s_redd[0];
      for (int w = 1; w < NWAVES; ++w) {
        if (s_redu[w] > b) b = s_redu[w];
        z += s_redd[w];
      }
      s_np = NW - 1 - (int)(b & 0xFFFFFFFFu);
      s_Z = (float)z;
    }
    __syncthreads();
    const int np = s_np;

    for (int j = tid; j < NW - 1; j += NTHREADS) {
      int a = (j < np) ? s_perm[j + (j >= pos)]
                       : ((j == np) ? tm : s_perm[(j - 1) + ((j - 1) >= pos)]);
      int j1 = j + 1;
      int b = (j1 < np) ? s_perm[j1 + (j1 >= pos)]
                        : ((j1 == np) ? tm : s_perm[(j1 - 1) + ((j1 - 1) >= pos)]);
      s_gath[j] = bigram[(u64)a * NW + b];
    }
    __syncthreads();

    if (tid == 0) {
      float S = 0.0f;
      for (int j = 0; j < NW - 1; ++j) S += s_gath[j];
      int s0 = (0 < np) ? s_perm[(0 >= pos) ? 1 : 0] : tm;
      int sl = ((NW - 1) == np) ? tm : s_perm[(NW - 2) + ((NW - 2) >= pos)];
      S = S + startv[s0];
      S = S + endv[sl];
      float dw = S - s_w;
      float e1 = (float)exp((double)dw);
      float en = (float)exp((double)(s_logit[np] - m));
      float eo = (float)exp((double)(s_logit[pos] - m));
      float pn = en / s_Z;
      float po = eo / s_Z;
      float acc = e1 * pn;
      acc = acc / po;
      acc = fminf(1.0f, acc);
      u32 ua, ub;
      tf2x32(s_ku0, s_ku1, 0u, 0u, &ua, &ub);
      float u = unif01(ua ^ ub);
      int accept = (acc > u) ? 1 : 0;
      s_acc = accept;
      if (accept) s_w = S;
    }
    __syncthreads();

    int stash[4];
    if (s_acc) {
      for (int k = 0; k < 4; ++k) {
        int i = tid + k * NTHREADS;
        stash[k] = (i < np) ? s_perm[i + (i >= pos)]
                            : ((i == np) ? tm : s_perm[(i - 1) + ((i - 1) >= pos)]);
      }
    }
    __syncthreads();
    if (s_acc) {
      for (int k = 0; k < 4; ++k) {
        int i = tid + k * NTHREADS;
        s_perm[i] = stash[k];
      }
    }
    __syncthreads();

    if (((t + 1) % 10) == 9) {
      int row = (t - 8) / 10;
      for (int i = tid; i < NW; i += NTHREADS) out[(u64)row * NW + i] = s_perm[i];
    }
    __syncthreads();
  }
}

extern "C" void kernel_launch(void* const* d_in, const int* in_sizes, int n_in,
                              void* d_out, int out_size, void* d_ws, size_t ws_size,
                              hipStream_t stream) {
  const float* bigram = (const float*)d_in[1];
  const float* startv = (const float*)d_in[2];
  const float* endv   = (const float*)d_in[3];
  int* out = (int*)d_out;

  const size_t needT = (size_t)NW * NW * sizeof(float);        // 64 MB
  const size_t needG = (size_t)NSTEPS * NW * sizeof(float);    // ~41.9 MB
  const size_t needP = (size_t)NSTEPS * (sizeof(int) + sizeof(float));

  if (ws_size >= needT + needG + needP) {
    float* bigT = (float*)d_ws;
    float* gumb = (float*)((char*)d_ws + needT);
    int* posArr = (int*)((char*)d_ws + needT + needG);
    float* uArr = (float*)((char*)d_ws + needT + needG + (size_t)NSTEPS * sizeof(int));
    hipLaunchKernelGGL(transpose_k, dim3(NW / TT, NW / TT), dim3(TT, 8), 0, stream,
                       bigram, bigT);
    long long ng = (long long)NSTEPS * NW;
    hipLaunchKernelGGL(gumbel_k, dim3((unsigned)((ng + 255) / 256)), dim3(256), 0, stream,
                       gumb);
    hipLaunchKernelGGL(posu_k, dim3((NSTEPS + 255) / 256), dim3(256), 0, stream,
                       posArr, uArr);
    hipLaunchKernelGGL(mcmc_fast9, dim3(1), dim3(NTHREADS), 0, stream,
                       bigram, bigT, gumb, posArr, uArr, startv, endv, out);
  } else {
    hipLaunchKernelGGL(mcmc_kernel, dim3(1), dim3(NTHREADS), 0, stream,
                       bigram, startv, endv, out);
  }
}

// Round 2
// 7521.349 us; speedup vs baseline: 1.9899x; 1.9899x over previous
//
#include <hip/hip_runtime.h>
#include <stdint.h>

// BetterMCMC R12: incremental-weight restructure.
//  - dw computed as a closed-form ~6-term f64 delta (remove-at-pos / insert-at-np through
//    perm2), not a 4096-element resum. Deletes s_pairw, newp, the per-step f64 reduce.
//    Perturbation vs verified full-sum path ~1e-5 abs in exp arg, inside the 2e-4 margin
//    band already survived. Exact 0 for the sample==perm cases (terms cancel bitwise).
//  - Accept known mid-step (wave0 computes it; others precompute both tm candidates) ->
//    single-branch row staging (32KB/step, half of R11's 64KB), issued right after the
//    B_mid barrier, overlapped with the perm commit.
//  - Specials/accept on wave0 only: removes the x16-wave broadcast-read duplication that
//    clogged the LDS pipe. lpos captured by the i==pos thread during Phase A.
//  - Keeps R11's verified pieces: DPP reductions, strided mapping, transposed gumbel,
//    Phase A logit formulas (bit-identical).

#define NW 4096
#define NSTEPS 2559
#define NTHREADS 1024
#define NWAVES 16

typedef unsigned long long u64;
typedef uint32_t u32;
typedef unsigned short u16;

__device__ __forceinline__ u32 rotl32(u32 v, u32 r) { return (v << r) | (v >> (32u - r)); }

// Threefry-2x32, 20 rounds, exactly as jax/_src/prng.py threefry2x32.
__device__ __forceinline__ void tf2x32(u32 k0, u32 k1, u32 x0, u32 x1, u32* o0, u32* o1) {
  u32 ks2 = k0 ^ k1 ^ 0x1BD11BDAu;
  x0 += k0; x1 += k1;
#define TFR(r0, r1, r2, r3)                      \
  x0 += x1; x1 = rotl32(x1, r0); x1 ^= x0;       \
  x0 += x1; x1 = rotl32(x1, r1); x1 ^= x0;       \
  x0 += x1; x1 = rotl32(x1, r2); x1 ^= x0;       \
  x0 += x1; x1 = rotl32(x1, r3); x1 ^= x0;
  TFR(13, 15, 26, 6)  x0 += k1;  x1 += ks2 + 1u;
  TFR(17, 29, 16, 24) x0 += ks2; x1 += k0 + 2u;
  TFR(13, 15, 26, 6)  x0 += k0;  x1 += k1 + 3u;
  TFR(17, 29, 16, 24) x0 += k1;  x1 += ks2 + 4u;
  TFR(13, 15, 26, 6)  x0 += ks2; x1 += k0 + 5u;
#undef TFR
  *o0 = x0; *o1 = x1;
}

__device__ __forceinline__ float unif01(u32 bits) {
  return __uint_as_float((bits >> 9) | 0x3f800000u) - 1.0f;
}

__device__ __forceinline__ u32 fkey(float f) {
  u32 b = __float_as_uint(f);
  return b ^ ((b >> 31) ? 0xFFFFFFFFu : 0x80000000u);
}

// ---------------- DPP argmax helpers (VALU, no LDS pipe) ----------------

template <int CTRL>
__device__ __forceinline__ u32 dpp32(u32 v) {
  return (u32)__builtin_amdgcn_update_dpp(0, (int)v, CTRL, 0xF, 0xF, true);
}

template <int CTRL>
__device__ __forceinline__ void dppmax64(u32& hi, u32& lo) {
  u32 h2 = dpp32<CTRL>(hi);
  u32 l2 = dpp32<CTRL>(lo);
  bool g = (h2 > hi) || (h2 == hi && l2 > lo);
  hi = g ? h2 : hi;
  lo = g ? l2 : lo;
}

// wave64 reduce; result valid in lane 63 (zero-fill: key 0 never wins)
__device__ __forceinline__ u64 wave_max_u64(u64 key) {
  u32 lo = (u32)key, hi = (u32)(key >> 32);
  dppmax64<0x111>(hi, lo); dppmax64<0x112>(hi, lo);
  dppmax64<0x114>(hi, lo); dppmax64<0x118>(hi, lo);
  dppmax64<0x142>(hi, lo); dppmax64<0x143>(hi, lo);
  return ((u64)hi << 32) | lo;
}

// 16-lane butterfly -> ALL lanes hold the result
__device__ __forceinline__ u64 bfly16_max_u64(u64 key) {
  u32 lo = (u32)key, hi = (u32)(key >> 32);
  dppmax64<0xB1>(hi, lo); dppmax64<0x4E>(hi, lo);
  dppmax64<0x141>(hi, lo); dppmax64<0x140>(hi, lo);
  return ((u64)hi << 32) | lo;
}

// ---------------- prep kernels (massively parallel) ----------------

#define TT 32
__global__ void transpose_k(const float* __restrict__ in, float* __restrict__ out) {
  __shared__ float tile[TT][TT + 1];
  int x = blockIdx.x * TT + threadIdx.x;
  int y = blockIdx.y * TT + threadIdx.y;
  for (int j = 0; j < TT; j += 8) tile[threadIdx.y + j][threadIdx.x] = in[(u64)(y + j) * NW + x];
  __syncthreads();
  x = blockIdx.y * TT + threadIdx.x;
  y = blockIdx.x * TT + threadIdx.y;
  for (int j = 0; j < TT; j += 8) out[(u64)(y + j) * NW + x] = tile[threadIdx.x][threadIdx.y + j];
}

// Pre-transposed within each step-row: slot p holds gumbel of element
// i = (p>>2) | ((p&3)<<10) so thread tid float4-loads elements {tid, tid+1024, ...}.
__global__ void gumbel_k(float* __restrict__ gumb) {
  long long idx = (long long)blockIdx.x * blockDim.x + threadIdx.x;
  if (idx >= (long long)NSTEPS * NW) return;
  int t = (int)(idx >> 12);
  int p = (int)(idx & (NW - 1));
  int i = (p >> 2) | ((p & 3) << 10);
  u32 kt0, kt1, kc0, kc1, ba, bb;
  tf2x32(0u, 42u, 0u, (u32)t, &kt0, &kt1);
  tf2x32(kt0, kt1, 0u, 1u, &kc0, &kc1);
  tf2x32(kc0, kc1, 0u, (u32)i, &ba, &bb);
  float u = unif01(ba ^ bb);
  if (u == 0.0f) u = 1.17549435e-38f;
  float t1 = (float)log((double)u);
  float t2 = (float)log((double)(-t1));
  gumb[idx] = -t2;
}

__global__ void posu_k(int* __restrict__ posArr, float* __restrict__ uArr) {
  int t = blockIdx.x * blockDim.x + threadIdx.x;
  if (t >= NSTEPS) return;
  u32 kt0, kt1, kp0, kp1, ku0, ku1, k2a, k2b, ra, rb, ua, ub;
  tf2x32(0u, 42u, 0u, (u32)t, &kt0, &kt1);
  tf2x32(kt0, kt1, 0u, 0u, &kp0, &kp1);
  tf2x32(kt0, kt1, 0u, 2u, &ku0, &ku1);
  tf2x32(kp0, kp1, 0u, 1u, &k2a, &k2b);
  tf2x32(k2a, k2b, 0u, 0u, &ra, &rb);
  posArr[t] = (int)((ra ^ rb) & (u32)(NW - 1));
  tf2x32(ku0, ku1, 0u, 0u, &ua, &ub);
  uArr[t] = unif01(ua ^ ub);
}

// ---------------- main chain kernel ----------------

// proposed sample element at index idx (reads pre-commit s_perm; uses np/pos/tm)
#define SAMPLE_AT(idx)                                                        \
  ((idx) < np ? (int)s_perm[(idx) + ((idx) >= pos)]                           \
              : ((idx) == np ? tm                                             \
                             : (int)s_perm[((idx)-1) + (((idx)-1) >= pos)]))

__global__ __launch_bounds__(NTHREADS)
void mcmc_fast10(const float* __restrict__ bigram,
                 const float* __restrict__ bigT,
                 const float* __restrict__ gumb,
                 const int* __restrict__ posArr,
                 const float* __restrict__ uArr,
                 const float* __restrict__ startv,
                 const float* __restrict__ endv,
                 int* __restrict__ out) {
  __shared__ u16    s_perm[NW];       // 8 KB
  __shared__ float  s_rowB[NW];       // 16 KB  bigram[tm, :]
  __shared__ float  s_rowT[NW];       // 16 KB  bigram[:, tm]
  __shared__ u64    s_redu[NWAVES];   // argmax partials
  __shared__ float  s_stm, s_etm, s_lpos;
  __shared__ int    s_accs;

  const int tid = threadIdx.x;
  const int lane = tid & 63;
  const int wid = tid >> 6;

  // ---- init: identity perm; stage step-0 rows ----
  for (int i = tid; i < NW; i += NTHREADS) s_perm[i] = (u16)i;

  int pos = posArr[0];
  int tm = pos;                        // identity perm: perm[pos] == pos
  {
    float4 rb4 = ((const float4*)(bigram + (u64)tm * NW))[tid];
    float4 rt4 = ((const float4*)(bigT + (u64)tm * NW))[tid];
    ((float4*)s_rowB)[tid] = rb4;
    ((float4*)s_rowT)[tid] = rt4;
  }
  if (tid == 0) { s_stm = startv[tm]; s_etm = endv[tm]; }

  // wave0-carried uniform chain state (garbage in other waves, never read there)
  float u_cur = uArr[0];
  float start_cur = startv[0];
  float end_cur = endv[NW - 1];
  float brg = 0.0f;
  if (pos >= 1 && pos <= NW - 2) brg = bigram[(u64)(pos - 1) * NW + (pos + 1)];

  float4 g4 = ((const float4*)gumb)[tid];
  __syncthreads();

  for (int t = 0; t < NSTEPS; ++t) {
    // ---- Phase A: logits + gumbel argmax (strided i = tid + k*1024) ----
    const float gg[4] = {g4.x, g4.y, g4.z, g4.w};
    int pos_nxt; float u_nxt;
    {
      int tn = (t + 1 < NSTEPS) ? (t + 1) : (NSTEPS - 1);
      g4 = ((const float4*)(gumb + ((u64)tn << 12)))[tid];   // for step t+1
      pos_nxt = posArr[tn];
      u_nxt = uArr[tn];
    }
    u64 best = 0;
#pragma unroll
    for (int k = 0; k < 4; ++k) {
      int i = tid + k * NTHREADS;
      float li;
      if (i == 0) {
        int r = s_perm[(0 >= pos) ? 1 : 0];
        li = s_stm + s_rowB[r];
      } else if (i == NW - 1) {
        int l = s_perm[((NW - 2) >= pos) ? (NW - 1) : (NW - 2)];
        li = s_etm + s_rowT[l];
      } else {
        int l = s_perm[(i - 1) + ((i - 1) >= pos)];
        int r = s_perm[i + (i >= pos)];
        li = s_rowT[l] + s_rowB[r];                  // fl(left + right), bit-identical
      }
      if (i == pos) s_lpos = li;                     // capture lpos for free
      float sv = gg[k] + li;
      u64 key = ((u64)fkey(sv) << 32) | (u32)(NW - 1 - i);
      if (key > best) best = key;
    }
    best = wave_max_u64(best);
    if (lane == 63) s_redu[wid] = best;
    __syncthreads();                                                  // B1

    // ---- Phase B: argmax finalize; stash + both-branch tm (all); accept (wave0) ----
    int np;
    {
      u64 bb = bfly16_max_u64(s_redu[lane & 15]);   // conflict-free, all lanes
      np = NW - 1 - (int)(bb & 0xFFFFFFFFu);
    }
    const int tmR = (int)s_perm[pos_nxt];
    const int tmA = SAMPLE_AT(pos_nxt);
    u16 stash[4];
#pragma unroll
    for (int k = 0; k < 4; ++k) {
      int j = tid + k * NTHREADS;
      stash[k] = (j < np) ? s_perm[j + (j >= pos)]
                          : ((j == np) ? (u16)tm : s_perm[(j - 1) + ((j - 1) >= pos)]);
    }
    int plA = 0, prA = 0, plR = 0, prR = 0;
    const bool ibn = (pos_nxt >= 1 && pos_nxt <= NW - 2);
    if (wid == 0) {
      // sample-edge indices (perm2[np-1], perm2[np]) -> split load issued ASAP
      int ls_i = (np >= 1) ? ((np - 1) + ((np - 1) >= pos)) : 0;
      int rs_i = (np <= NW - 2) ? (np + (np >= pos)) : 0;
      const int l_s = (int)s_perm[ls_i];
      const int r_s = (int)s_perm[rs_i];
      float splitv = bigram[(u64)l_s * NW + r_s];          // L3-hot broadcast load
      int s0 = (np > 0) ? (int)s_perm[(0 >= pos) ? 1 : 0] : tm;
      int sl = (np < NW - 1) ? (int)s_perm[(NW - 2) + ((NW - 2) >= pos)] : tm;
      float sv0 = startv[s0];
      float ev1 = endv[sl];
      float remL = 0.0f, remR = 0.0f;
      if (pos > 0)      remL = s_rowT[s_perm[pos - 1]];    // B[P[pos-1], tm]
      if (pos < NW - 1) remR = s_rowB[s_perm[pos + 1]];    // B[tm, P[pos+1]]
      float vnpm1 = (np >= 1)      ? s_rowT[l_s] : 0.0f;   // B[perm2[np-1], tm]
      float vnp   = (np <= NW - 2) ? s_rowB[r_s] : 0.0f;   // B[tm, perm2[np]]
      // bridge candidates for step t+1 (both branches, pre-commit reads)
      if (ibn) {
        plR = (int)s_perm[pos_nxt - 1]; prR = (int)s_perm[pos_nxt + 1];
        plA = SAMPLE_AT(pos_nxt - 1);   prA = SAMPLE_AT(pos_nxt + 1);
      }
      float stm_r = s_stm, etm_r = s_etm;
      float lposv = s_lpos;
      // closed-form dw = W(sample) - W(perm), f64
      double delta = 0.0;
      if (pos > 0)               delta -= (double)remL;
      if (pos < NW - 1)          delta -= (double)remR;
      if (pos > 0 && pos < NW-1) delta += (double)brg;
      if (np > 0)                delta += (double)vnpm1;
      if (np < NW - 1)           delta += (double)vnp;
      if (np > 0 && np < NW - 1) delta -= (double)splitv;
      delta += ((double)sv0 - (double)start_cur) + ((double)ev1 - (double)end_cur);
      // lnp needs no new reads: fl(vnpm1+vnp) matches the Phase A formula bitwise
      float lnp = (np == 0) ? (stm_r + vnp)
                : ((np == NW - 1) ? (etm_r + vnpm1) : (vnpm1 + vnp));
      double ed = delta + ((double)lnp - (double)lposv);
      float a = fminf(1.0f, (float)exp(ed));
      int acc = (a > u_cur) ? 1 : 0;
      if (lane == 0) s_accs = acc;
      if (acc) { start_cur = sv0; end_cur = ev1; }
    }
    __syncthreads();                                                  // B_mid

    // ---- Phase C: select branch; single-branch row load overlapped with commit ----
    const int acc = s_accs;
    const int tm_next = acc ? tmA : tmR;
    const float4 rb4 = ((const float4*)(bigram + (u64)tm_next * NW))[tid];  // issue early
    const float4 rt4 = ((const float4*)(bigT + (u64)tm_next * NW))[tid];
    if (wid == 0) {
      float stmN = startv[tm_next];
      float etmN = endv[tm_next];
      brg = 0.0f;
      if (ibn) {
        int pl = acc ? plA : plR;
        int pr = acc ? prA : prR;
        brg = bigram[(u64)pl * NW + pr];                   // bridge for step t+1
      }
      if (lane == 0) { s_stm = stmN; s_etm = etmN; }
    }
    if (acc) {
#pragma unroll
      for (int k = 0; k < 4; ++k) {
        int j = tid + k * NTHREADS;
        s_perm[j] = stash[k];
      }
    }
    ((float4*)s_rowB)[tid] = rb4;   // vmcnt wait lands here, after commit overlap
    ((float4*)s_rowT)[tid] = rt4;
    tm = tm_next;
    pos = pos_nxt;
    u_cur = u_nxt;
    __syncthreads();                                                  // B_end

    // ---- emit thinned sample (reads committed perm, post-barrier) ----
    if ((t % 10) == 8) {
      int row = (t - 8) / 10;
      ushort4 p4 = ((const ushort4*)s_perm)[tid];
      int4 o4;
      o4.x = (int)p4.x; o4.y = (int)p4.y; o4.z = (int)p4.z; o4.w = (int)p4.w;
      ((int4*)(out + (u64)row * NW))[tid] = o4;
    }
  }
}

// ---------------- fallback (R2 kernel, verified) ----------------

__global__ __launch_bounds__(NTHREADS)
void mcmc_kernel(const float* __restrict__ bigram,
                 const float* __restrict__ startv,
                 const float* __restrict__ endv,
                 int* __restrict__ out) {
  __shared__ int    s_perm[NW];
  __shared__ float  s_logit[NW];
  __shared__ float  s_gath[NW];
  __shared__ float  s_redf[NWAVES];
  __shared__ u64    s_redu[NWAVES];
  __shared__ double s_redd[NWAVES];
  __shared__ float  s_m, s_Z, s_w;
  __shared__ int    s_pos, s_tm, s_np, s_acc;
  __shared__ u32    s_kcat0, s_kcat1, s_ku0, s_ku1;

  const int tid = threadIdx.x;
  const int lane = tid & 63;
  const int wid = tid >> 6;

  for (int i = tid; i < NW; i += NTHREADS) s_perm[i] = i;
  for (int j = tid; j < NW - 1; j += NTHREADS) s_gath[j] = bigram[(u64)j * NW + (j + 1)];
  __syncthreads();
  if (tid == 0) {
    float S = 0.0f;
    for (int j = 0; j < NW - 1; ++j) S += s_gath[j];
    S = S + startv[0];
    S = S + endv[NW - 1];
    s_w = S;
  }
  __syncthreads();

  for (int t = 0; t < NSTEPS; ++t) {
    if (tid == 0) {
      u32 kt0, kt1;
      tf2x32(0u, 42u, 0u, (u32)t, &kt0, &kt1);
      u32 kp0, kp1, kc0, kc1, ku0, ku1;
      tf2x32(kt0, kt1, 0u, 0u, &kp0, &kp1);
      tf2x32(kt0, kt1, 0u, 1u, &kc0, &kc1);
      tf2x32(kt0, kt1, 0u, 2u, &ku0, &ku1);
      u32 k2a, k2b, ra, rb;
      tf2x32(kp0, kp1, 0u, 1u, &k2a, &k2b);
      tf2x32(k2a, k2b, 0u, 0u, &ra, &rb);
      int pos = (int)((ra ^ rb) & (u32)(NW - 1));
      s_pos = pos;
      s_tm = s_perm[pos];
      s_kcat0 = kc0; s_kcat1 = kc1; s_ku0 = ku0; s_ku1 = ku1;
    }
    __syncthreads();
    const int pos = s_pos, tm = s_tm;

    float lmax = -3.402823466e+38f;
    for (int i = tid; i < NW; i += NTHREADS) {
      float li;
      if (i == 0) {
        int r = s_perm[(0 >= pos) ? 1 : 0];
        li = startv[tm] + bigram[(u64)tm * NW + r];
      } else if (i == NW - 1) {
        int l = s_perm[((NW - 2) >= pos) ? (NW - 1) : (NW - 2)];
        li = endv[tm] + bigram[(u64)l * NW + tm];
      } else {
        int l = s_perm[((i - 1) >= pos) ? i : (i - 1)];
        int r = s_perm[(i >= pos) ? (i + 1) : i];
        li = bigram[(u64)l * NW + tm] + bigram[(u64)tm * NW + r];
      }
      s_logit[i] = li;
      lmax = fmaxf(lmax, li);
    }
    for (int o = 32; o > 0; o >>= 1) lmax = fmaxf(lmax, __shfl_down(lmax, o, 64));
    if (lane == 0) s_redf[wid] = lmax;
    __syncthreads();
    if (tid == 0) {
      float m = s_redf[0];
      for (int w = 1; w < NWAVES; ++w) m = fmaxf(m, s_redf[w]);
      s_m = m;
    }
    __syncthreads();
    const float m = s_m;

    double zacc = 0.0;
    u64 best = 0;
    const u32 kc0 = s_kcat0, kc1 = s_kcat1;
    for (int i = tid; i < NW; i += NTHREADS) {
      float li = s_logit[i];
      float ex = (float)exp((double)(li - m));
      zacc += (double)ex;
      u32 ba, bb;
      tf2x32(kc0, kc1, 0u, (u32)i, &ba, &bb);
      float u = unif01(ba ^ bb);
      if (u == 0.0f) u = 1.17549435e-38f;
      float t1 = (float)log((double)u);
      float t2 = (float)log((double)(-t1));
      float g = -t2;
      float sv = g + li;
      u64 key = ((u64)fkey(sv) << 32) | (u32)(NW - 1 - i);
      if (key > best) best = key;
    }
    for (int o = 32; o > 0; o >>= 1) {
      u64 w = __shfl_down(best, o, 64);
      if (w > best) best = w;
      zacc += __shfl_down(zacc, o, 64);
    }
    if (lane == 0) { s_redu[wid] = best; s_redd[wid] = zacc; }
    __syncthreads();
    if (tid == 0) {
      u64 b = s_redu[0]; double z = s_redd[0];
      for (int w = 1; w < NWAVES; ++w) {
        if (s_redu[w] > b) b = s_redu[w];
        z += s_redd[w];
      }
      s_np = NW - 1 - (int)(b & 0xFFFFFFFFu);
      s_Z = (float)z;
    }
    __syncthreads();
    const int np = s_np;

    for (int j = tid; j < NW - 1; j += NTHREADS) {
      int a = (j < np) ? s_perm[j + (j >= pos)]
                       : ((j == np) ? tm : s_perm[(j - 1) + ((j - 1) >= pos)]);
      int j1 = j + 1;
      int b = (j1 < np) ? s_perm[j1 + (j1 >= pos)]
                        : ((j1 == np) ? tm : s_perm[(j1 - 1) + ((j1 - 1) >= pos)]);
      s_gath[j] = bigram[(u64)a * NW + b];
    }
    __syncthreads();

    if (tid == 0) {
      float S = 0.0f;
      for (int j = 0; j < NW - 1; ++j) S += s_gath[j];
      int s0 = (0 < np) ? s_perm[(0 >= pos) ? 1 : 0] : tm;
      int sl = ((NW - 1) == np) ? tm : s_perm[(NW - 2) + ((NW - 2) >= pos)];
      S = S + startv[s0];
      S = S + endv[sl];
      float dw = S - s_w;
      float e1 = (float)exp((double)dw);
      float en = (float)exp((double)(s_logit[np] - m));
      float eo = (float)exp((double)(s_logit[pos] - m));
      float pn = en / s_Z;
      float po = eo / s_Z;
      float acc = e1 * pn;
      acc = acc / po;
      acc = fminf(1.0f, acc);
      u32 ua, ub;
      tf2x32(s_ku0, s_ku1, 0u, 0u, &ua, &ub);
      float u = unif01(ua ^ ub);
      int accept = (acc > u) ? 1 : 0;
      s_acc = accept;
      if (accept) s_w = S;
    }
    __syncthreads();

    int stash[4];
    if (s_acc) {
      for (int k = 0; k < 4; ++k) {
        int i = tid + k * NTHREADS;
        stash[k] = (i < np) ? s_perm[i + (i >= pos)]
                            : ((i == np) ? tm : s_perm[(i - 1) + ((i - 1) >= pos)]);
      }
    }
    __syncthreads();
    if (s_acc) {
      for (int k = 0; k < 4; ++k) {
        int i = tid + k * NTHREADS;
        s_perm[i] = stash[k];
      }
    }
    __syncthreads();

    if (((t + 1) % 10) == 9) {
      int row = (t - 8) / 10;
      for (int i = tid; i < NW; i += NTHREADS) out[(u64)row * NW + i] = s_perm[i];
    }
    __syncthreads();
  }
}

extern "C" void kernel_launch(void* const* d_in, const int* in_sizes, int n_in,
                              void* d_out, int out_size, void* d_ws, size_t ws_size,
                              hipStream_t stream) {
  const float* bigram = (const float*)d_in[1];
  const float* startv = (const float*)d_in[2];
  const float* endv   = (const float*)d_in[3];
  int* out = (int*)d_out;

  const size_t needT = (size_t)NW * NW * sizeof(float);        // 64 MB
  const size_t needG = (size_t)NSTEPS * NW * sizeof(float);    // ~41.9 MB
  const size_t needP = (size_t)NSTEPS * (sizeof(int) + sizeof(float));

  if (ws_size >= needT + needG + needP) {
    float* bigT = (float*)d_ws;
    float* gumb = (float*)((char*)d_ws + needT);
    int* posArr = (int*)((char*)d_ws + needT + needG);
    float* uArr = (float*)((char*)d_ws + needT + needG + (size_t)NSTEPS * sizeof(int));
    hipLaunchKernelGGL(transpose_k, dim3(NW / TT, NW / TT), dim3(TT, 8), 0, stream,
                       bigram, bigT);
    long long ng = (long long)NSTEPS * NW;
    hipLaunchKernelGGL(gumbel_k, dim3((unsigned)((ng + 255) / 256)), dim3(256), 0, stream,
                       gumb);
    hipLaunchKernelGGL(posu_k, dim3((NSTEPS + 255) / 256), dim3(256), 0, stream,
                       posArr, uArr);
    hipLaunchKernelGGL(mcmc_fast10, dim3(1), dim3(NTHREADS), 0, stream,
                       bigram, bigT, gumb, posArr, uArr, startv, endv, out);
  } else {
    hipLaunchKernelGGL(mcmc_kernel, dim3(1), dim3(NTHREADS), 0, stream,
                       bigram, startv, endv, out);
  }
}

// Round 3
// 6689.148 us; speedup vs baseline: 2.2375x; 1.1244x over previous
//
#include <hip/hip_runtime.h>
#include <stdint.h>

// BetterMCMC R13: register-resident perm blocks + interleaved row table.
//  - Contiguous element mapping (thread t owns 4t..4t+3): perm block = 1 ds_read_b64;
//    neighbors via DPP wave_shr1/wave_shl1 (VALU, off the LDS pipe); edge lanes patch
//    with one exec-masked LDS read per wave.
//  - s_rows[w] = (T[w], B[w]) interleaved: r(i) = l(i+1) -> one b64 gather serves two
//    elements. Phase A gathers 8 -> 4 (+1 DPP edge pass). Adds in same order ->
//    bit-identical logits.
//  - Stash fully register-resident; commit = 1 ds_write_b64; row staging = 2
//    interleaved b128 writes. LDS wave-instrs/step ~450 -> ~145.
//  - expf((float)ed) replaces f64 exp in wave0's serial accept (~300 -> ~30 cy);
//    <=1 ulp perturbation on a, flip probability ~3e-4 over the chain.
// Everything else (closed-form delta, wave0 accept, single-branch staging, DPP
// reductions) carried from verified R12.

#define NW 4096
#define NSTEPS 2559
#define NTHREADS 1024
#define NWAVES 16

typedef unsigned long long u64;
typedef uint32_t u32;
typedef unsigned short u16;

__device__ __forceinline__ u32 rotl32(u32 v, u32 r) { return (v << r) | (v >> (32u - r)); }

// Threefry-2x32, 20 rounds, exactly as jax/_src/prng.py threefry2x32.
__device__ __forceinline__ void tf2x32(u32 k0, u32 k1, u32 x0, u32 x1, u32* o0, u32* o1) {
  u32 ks2 = k0 ^ k1 ^ 0x1BD11BDAu;
  x0 += k0; x1 += k1;
#define TFR(r0, r1, r2, r3)                      \
  x0 += x1; x1 = rotl32(x1, r0); x1 ^= x0;       \
  x0 += x1; x1 = rotl32(x1, r1); x1 ^= x0;       \
  x0 += x1; x1 = rotl32(x1, r2); x1 ^= x0;       \
  x0 += x1; x1 = rotl32(x1, r3); x1 ^= x0;
  TFR(13, 15, 26, 6)  x0 += k1;  x1 += ks2 + 1u;
  TFR(17, 29, 16, 24) x0 += ks2; x1 += k0 + 2u;
  TFR(13, 15, 26, 6)  x0 += k0;  x1 += k1 + 3u;
  TFR(17, 29, 16, 24) x0 += k1;  x1 += ks2 + 4u;
  TFR(13, 15, 26, 6)  x0 += ks2; x1 += k0 + 5u;
#undef TFR
  *o0 = x0; *o1 = x1;
}

__device__ __forceinline__ float unif01(u32 bits) {
  return __uint_as_float((bits >> 9) | 0x3f800000u) - 1.0f;
}

__device__ __forceinline__ u32 fkey(float f) {
  u32 b = __float_as_uint(f);
  return b ^ ((b >> 31) ? 0xFFFFFFFFu : 0x80000000u);
}

// ---------------- DPP helpers (VALU, no LDS pipe) ----------------
// row_shr:n / wave_shr1 (0x138): dest lane n <- src lane n-1 (data moves to higher lanes)
// wave_shl1 (0x130): dest lane n <- src lane n+1. bound_ctrl=true -> invalid src = 0.

template <int CTRL>
__device__ __forceinline__ u32 dpp32(u32 v) {
  return (u32)__builtin_amdgcn_update_dpp(0, (int)v, CTRL, 0xF, 0xF, true);
}

template <int CTRL>
__device__ __forceinline__ void dppmax64(u32& hi, u32& lo) {
  u32 h2 = dpp32<CTRL>(hi);
  u32 l2 = dpp32<CTRL>(lo);
  bool g = (h2 > hi) || (h2 == hi && l2 > lo);
  hi = g ? h2 : hi;
  lo = g ? l2 : lo;
}

// wave64 reduce; result valid in lane 63 (zero-fill: key 0 never wins)
__device__ __forceinline__ u64 wave_max_u64(u64 key) {
  u32 lo = (u32)key, hi = (u32)(key >> 32);
  dppmax64<0x111>(hi, lo); dppmax64<0x112>(hi, lo);
  dppmax64<0x114>(hi, lo); dppmax64<0x118>(hi, lo);
  dppmax64<0x142>(hi, lo); dppmax64<0x143>(hi, lo);
  return ((u64)hi << 32) | lo;
}

// 16-lane butterfly -> ALL lanes hold the result
__device__ __forceinline__ u64 bfly16_max_u64(u64 key) {
  u32 lo = (u32)key, hi = (u32)(key >> 32);
  dppmax64<0xB1>(hi, lo); dppmax64<0x4E>(hi, lo);
  dppmax64<0x141>(hi, lo); dppmax64<0x140>(hi, lo);
  return ((u64)hi << 32) | lo;
}

// ---------------- prep kernels (massively parallel) ----------------

#define TT 32
__global__ void transpose_k(const float* __restrict__ in, float* __restrict__ out) {
  __shared__ float tile[TT][TT + 1];
  int x = blockIdx.x * TT + threadIdx.x;
  int y = blockIdx.y * TT + threadIdx.y;
  for (int j = 0; j < TT; j += 8) tile[threadIdx.y + j][threadIdx.x] = in[(u64)(y + j) * NW + x];
  __syncthreads();
  x = blockIdx.y * TT + threadIdx.x;
  y = blockIdx.x * TT + threadIdx.y;
  for (int j = 0; j < TT; j += 8) out[(u64)(y + j) * NW + x] = tile[threadIdx.x][threadIdx.y + j];
}

// Natural layout: gumb[t*NW + i] = gumbel for element i at step t.
__global__ void gumbel_k(float* __restrict__ gumb) {
  long long idx = (long long)blockIdx.x * blockDim.x + threadIdx.x;
  if (idx >= (long long)NSTEPS * NW) return;
  int t = (int)(idx >> 12);
  int i = (int)(idx & (NW - 1));
  u32 kt0, kt1, kc0, kc1, ba, bb;
  tf2x32(0u, 42u, 0u, (u32)t, &kt0, &kt1);
  tf2x32(kt0, kt1, 0u, 1u, &kc0, &kc1);
  tf2x32(kc0, kc1, 0u, (u32)i, &ba, &bb);
  float u = unif01(ba ^ bb);
  if (u == 0.0f) u = 1.17549435e-38f;
  float t1 = (float)log((double)u);
  float t2 = (float)log((double)(-t1));
  gumb[idx] = -t2;
}

__global__ void posu_k(int* __restrict__ posArr, float* __restrict__ uArr) {
  int t = blockIdx.x * blockDim.x + threadIdx.x;
  if (t >= NSTEPS) return;
  u32 kt0, kt1, kp0, kp1, ku0, ku1, k2a, k2b, ra, rb, ua, ub;
  tf2x32(0u, 42u, 0u, (u32)t, &kt0, &kt1);
  tf2x32(kt0, kt1, 0u, 0u, &kp0, &kp1);
  tf2x32(kt0, kt1, 0u, 2u, &ku0, &ku1);
  tf2x32(kp0, kp1, 0u, 1u, &k2a, &k2b);
  tf2x32(k2a, k2b, 0u, 0u, &ra, &rb);
  posArr[t] = (int)((ra ^ rb) & (u32)(NW - 1));
  tf2x32(ku0, ku1, 0u, 0u, &ua, &ub);
  uArr[t] = unif01(ua ^ ub);
}

// ---------------- main chain kernel ----------------

// proposed sample element at index idx (reads pre-commit s_perm; uses np/pos/tm)
#define SAMPLE_AT(idx)                                                        \
  ((idx) < np ? (int)s_perm[(idx) + ((idx) >= pos)]                           \
              : ((idx) == np ? tm                                             \
                             : (int)s_perm[((idx)-1) + (((idx)-1) >= pos)]))

__global__ __launch_bounds__(NTHREADS)
void mcmc_fast11(const float* __restrict__ bigram,
                 const float* __restrict__ bigT,
                 const float* __restrict__ gumb,
                 const int* __restrict__ posArr,
                 const float* __restrict__ uArr,
                 const float* __restrict__ startv,
                 const float* __restrict__ endv,
                 int* __restrict__ out) {
  __shared__ u16    s_perm[NW];       // 8 KB
  __shared__ float2 s_rows[NW];       // 32 KB  (T[w], B[w]) for current tm
  __shared__ u64    s_redu[NWAVES];
  __shared__ float  s_stm, s_etm, s_lpos;
  __shared__ int    s_accs;

  const int tid = threadIdx.x;
  const int lane = tid & 63;
  const int wid = tid >> 6;
  const int j0 = tid * 4;             // first owned element

  // ---- init: identity perm; stage step-0 rows (interleaved) ----
  for (int i = tid; i < NW; i += NTHREADS) s_perm[i] = (u16)i;

  int pos = posArr[0];
  int tm = pos;                        // identity perm: perm[pos] == pos
  {
    float4 rb4 = ((const float4*)(bigram + (u64)tm * NW))[tid];
    float4 rt4 = ((const float4*)(bigT + (u64)tm * NW))[tid];
    ((float4*)(&s_rows[j0]))[0] = make_float4(rt4.x, rb4.x, rt4.y, rb4.y);
    ((float4*)(&s_rows[j0]))[1] = make_float4(rt4.z, rb4.z, rt4.w, rb4.w);
  }
  if (tid == 0) { s_stm = startv[tm]; s_etm = endv[tm]; }

  // wave0-carried uniform chain state (garbage in other waves, never read there)
  float u_cur = uArr[0];
  float start_cur = startv[0];
  float end_cur = endv[NW - 1];
  float brg = 0.0f;
  if (pos >= 1 && pos <= NW - 2) brg = bigram[(u64)(pos - 1) * NW + (pos + 1)];

  float4 g4 = ((const float4*)gumb)[tid];
  __syncthreads();

  for (int t = 0; t < NSTEPS; ++t) {
    // ---- Phase A: logits + gumbel argmax (contiguous, register perm block) ----
    const float gg[4] = {g4.x, g4.y, g4.z, g4.w};
    int pos_nxt; float u_nxt;
    {
      int tn = (t + 1 < NSTEPS) ? (t + 1) : (NSTEPS - 1);
      g4 = ((const float4*)(gumb + ((u64)tn << 12)))[tid];   // for step t+1
      pos_nxt = posArr[tn];
      u_nxt = uArr[tn];
    }
    // perm block + neighbors
    ushort4 pq = ((const ushort4*)s_perm)[tid];              // perm[j0..j0+3]
    const int p0i = pq.x, p1i = pq.y, p2i = pq.z, p3i = pq.w;
    int pm1, pp4;
    {
      u32 lo = (u32)pq.x | ((u32)pq.y << 16);
      u32 hi = (u32)pq.z | ((u32)pq.w << 16);
      pm1 = (int)(dpp32<0x138>(hi) >> 16);                   // lane-1's p3 = perm[j0-1]
      pp4 = (int)(dpp32<0x130>(lo) & 0xFFFFu);               // lane+1's p0 = perm[j0+4]
      if (lane == 0)  pm1 = (tid > 0) ? (int)s_perm[j0 - 1] : 0;
      if (lane == 63) pp4 = (tid < NTHREADS - 1) ? (int)s_perm[j0 + 4] : 0;
    }
    // perm2 values for owned j (register selects)
    const int w0 = (j0     >= pos) ? p1i : p0i;
    const int w1 = (j0 + 1 >= pos) ? p2i : p1i;
    const int w2 = (j0 + 2 >= pos) ? p3i : p2i;
    const int w3 = (j0 + 3 >= pos) ? pp4 : p3i;
    const int wprev = ((j0 - 1) >= pos) ? p0i : pm1;         // perm2[j0-1]
    // interleaved gathers: f_k = (T[w_k], B[w_k])
    const float2 f0 = s_rows[w0];
    const float2 f1 = s_rows[w1];
    const float2 f2 = s_rows[w2];
    const float2 f3 = s_rows[w3];
    // T at perm2[j0-1] from lane-1's f3.x (DPP); wave-edge lanes read directly
    float tprev = __uint_as_float(dpp32<0x138>(__float_as_uint(f3.x)));
    if (lane == 0 && tid > 0) tprev = s_rows[wprev].x;
    // logits (bit-identical adds: T + B)
    float li0 = tprev + f0.y;
    float li1 = f0.x + f1.y;
    float li2 = f1.x + f2.y;
    float li3 = f2.x + f3.y;
    if (tid == 0)            li0 = s_stm + f0.y;
    if (tid == NTHREADS - 1) li3 = s_etm + f2.x;
    if ((pos >> 2) == tid) {
      int k = pos & 3;
      s_lpos = (k == 0) ? li0 : ((k == 1) ? li1 : ((k == 2) ? li2 : li3));
    }
    u64 best;
    {
      u64 b0 = ((u64)fkey(gg[0] + li0) << 32) | (u32)(NW - 1 - j0);
      u64 b1 = ((u64)fkey(gg[1] + li1) << 32) | (u32)(NW - 2 - j0);
      u64 b2 = ((u64)fkey(gg[2] + li2) << 32) | (u32)(NW - 3 - j0);
      u64 b3 = ((u64)fkey(gg[3] + li3) << 32) | (u32)(NW - 4 - j0);
      best = b0 > b1 ? b0 : b1;
      u64 b23 = b2 > b3 ? b2 : b3;
      if (b23 > best) best = b23;
    }
    best = wave_max_u64(best);
    if (lane == 63) s_redu[wid] = best;
    __syncthreads();                                                  // B1

    // ---- Phase B: argmax finalize; register stash; wave0 accept ----
    int np;
    {
      u64 bb = bfly16_max_u64(s_redu[lane & 15]);
      np = NW - 1 - (int)(bb & 0xFFFFFFFFu);
    }
    const int tmR = (int)s_perm[pos_nxt];
    const int tmA = SAMPLE_AT(pos_nxt);
    ushort4 st;
    st.x = (j0     < np) ? (u16)w0 : ((j0     == np) ? (u16)tm : (u16)wprev);
    st.y = (j0 + 1 < np) ? (u16)w1 : ((j0 + 1 == np) ? (u16)tm : (u16)w0);
    st.z = (j0 + 2 < np) ? (u16)w2 : ((j0 + 2 == np) ? (u16)tm : (u16)w1);
    st.w = (j0 + 3 < np) ? (u16)w3 : ((j0 + 3 == np) ? (u16)tm : (u16)w2);
    int plA = 0, prA = 0, plR = 0, prR = 0;
    const bool ibn = (pos_nxt >= 1 && pos_nxt <= NW - 2);
    if (wid == 0) {
      int ls_i = (np >= 1) ? ((np - 1) + ((np - 1) >= pos)) : 0;
      int rs_i = (np <= NW - 2) ? (np + (np >= pos)) : 0;
      const int l_s = (int)s_perm[ls_i];
      const int r_s = (int)s_perm[rs_i];
      float splitv = bigram[(u64)l_s * NW + r_s];            // L3-hot broadcast load
      int s0 = (np > 0) ? (int)s_perm[(0 >= pos) ? 1 : 0] : tm;
      int sl = (np < NW - 1) ? (int)s_perm[(NW - 2) + ((NW - 2) >= pos)] : tm;
      float sv0 = startv[s0];
      float ev1 = endv[sl];
      float remL = 0.0f, remR = 0.0f;
      if (pos > 0)      remL = s_rows[s_perm[pos - 1]].x;    // B[P[pos-1], tm]
      if (pos < NW - 1) remR = s_rows[s_perm[pos + 1]].y;    // B[tm, P[pos+1]]
      float vnpm1 = (np >= 1)      ? s_rows[l_s].x : 0.0f;
      float vnp   = (np <= NW - 2) ? s_rows[r_s].y : 0.0f;
      if (ibn) {
        plR = (int)s_perm[pos_nxt - 1]; prR = (int)s_perm[pos_nxt + 1];
        plA = SAMPLE_AT(pos_nxt - 1);   prA = SAMPLE_AT(pos_nxt + 1);
      }
      float stm_r = s_stm, etm_r = s_etm;
      float lposv = s_lpos;
      double delta = 0.0;
      if (pos > 0)                 delta -= (double)remL;
      if (pos < NW - 1)            delta -= (double)remR;
      if (pos > 0 && pos < NW - 1) delta += (double)brg;
      if (np > 0)                  delta += (double)vnpm1;
      if (np < NW - 1)             delta += (double)vnp;
      if (np > 0 && np < NW - 1)   delta -= (double)splitv;
      delta += ((double)sv0 - (double)start_cur) + ((double)ev1 - (double)end_cur);
      float lnp = (np == 0) ? (stm_r + vnp)
                : ((np == NW - 1) ? (etm_r + vnpm1) : (vnpm1 + vnp));
      double ed = delta + ((double)lnp - (double)lposv);
      float a = fminf(1.0f, expf((float)ed));
      int acc = (a > u_cur) ? 1 : 0;
      if (lane == 0) s_accs = acc;
      if (acc) { start_cur = sv0; end_cur = ev1; }
    }
    __syncthreads();                                                  // B_mid

    // ---- Phase C: select branch; row load overlapped with commit ----
    const int acc = s_accs;
    const int tm_next = acc ? tmA : tmR;
    const float4 rb4 = ((const float4*)(bigram + (u64)tm_next * NW))[tid];
    const float4 rt4 = ((const float4*)(bigT + (u64)tm_next * NW))[tid];
    if (wid == 0) {
      float stmN = startv[tm_next];
      float etmN = endv[tm_next];
      brg = 0.0f;
      if (ibn) {
        int pl = acc ? plA : plR;
        int pr = acc ? prA : prR;
        brg = bigram[(u64)pl * NW + pr];                     // bridge for step t+1
      }
      if (lane == 0) { s_stm = stmN; s_etm = etmN; }
    }
    if (acc) ((ushort4*)s_perm)[tid] = st;                   // 1 ds_write_b64
    ((float4*)(&s_rows[j0]))[0] = make_float4(rt4.x, rb4.x, rt4.y, rb4.y);
    ((float4*)(&s_rows[j0]))[1] = make_float4(rt4.z, rb4.z, rt4.w, rb4.w);
    tm = tm_next;
    pos = pos_nxt;
    u_cur = u_nxt;
    __syncthreads();                                                  // B_end

    // ---- emit thinned sample ----
    if ((t % 10) == 8) {
      int row = (t - 8) / 10;
      ushort4 p4 = ((const ushort4*)s_perm)[tid];
      int4 o4;
      o4.x = (int)p4.x; o4.y = (int)p4.y; o4.z = (int)p4.z; o4.w = (int)p4.w;
      ((int4*)(out + (u64)row * NW))[tid] = o4;
    }
  }
}

// ---------------- fallback (R2 kernel, verified) ----------------

__global__ __launch_bounds__(NTHREADS)
void mcmc_kernel(const float* __restrict__ bigram,
                 const float* __restrict__ startv,
                 const float* __restrict__ endv,
                 int* __restrict__ out) {
  __shared__ int    s_perm[NW];
  __shared__ float  s_logit[NW];
  __shared__ float  s_gath[NW];
  __shared__ float  s_redf[NWAVES];
  __shared__ u64    s_redu[NWAVES];
  __shared__ double s_redd[NWAVES];
  __shared__ float  s_m, s_Z, s_w;
  __shared__ int    s_pos, s_tm, s_np, s_acc;
  __shared__ u32    s_kcat0, s_kcat1, s_ku0, s_ku1;

  const int tid = threadIdx.x;
  const int lane = tid & 63;
  const int wid = tid >> 6;

  for (int i = tid; i < NW; i += NTHREADS) s_perm[i] = i;
  for (int j = tid; j < NW - 1; j += NTHREADS) s_gath[j] = bigram[(u64)j * NW + (j + 1)];
  __syncthreads();
  if (tid == 0) {
    float S = 0.0f;
    for (int j = 0; j < NW - 1; ++j) S += s_gath[j];
    S = S + startv[0];
    S = S + endv[NW - 1];
    s_w = S;
  }
  __syncthreads();

  for (int t = 0; t < NSTEPS; ++t) {
    if (tid == 0) {
      u32 kt0, kt1;
      tf2x32(0u, 42u, 0u, (u32)t, &kt0, &kt1);
      u32 kp0, kp1, kc0, kc1, ku0, ku1;
      tf2x32(kt0, kt1, 0u, 0u, &kp0, &kp1);
      tf2x32(kt0, kt1, 0u, 1u, &kc0, &kc1);
      tf2x32(kt0, kt1, 0u, 2u, &ku0, &ku1);
      u32 k2a, k2b, ra, rb;
      tf2x32(kp0, kp1, 0u, 1u, &k2a, &k2b);
      tf2x32(k2a, k2b, 0u, 0u, &ra, &rb);
      int pos = (int)((ra ^ rb) & (u32)(NW - 1));
      s_pos = pos;
      s_tm = s_perm[pos];
      s_kcat0 = kc0; s_kcat1 = kc1; s_ku0 = ku0; s_ku1 = ku1;
    }
    __syncthreads();
    const int pos = s_pos, tm = s_tm;

    float lmax = -3.402823466e+38f;
    for (int i = tid; i < NW; i += NTHREADS) {
      float li;
      if (i == 0) {
        int r = s_perm[(0 >= pos) ? 1 : 0];
        li = startv[tm] + bigram[(u64)tm * NW + r];
      } else if (i == NW - 1) {
        int l = s_perm[((NW - 2) >= pos) ? (NW - 1) : (NW - 2)];
        li = endv[tm] + bigram[(u64)l * NW + tm];
      } else {
        int l = s_perm[((i - 1) >= pos) ? i : (i - 1)];
        int r = s_perm[(i >= pos) ? (i + 1) : i];
        li = bigram[(u64)l * NW + tm] + bigram[(u64)tm * NW + r];
      }
      s_logit[i] = li;
      lmax = fmaxf(lmax, li);
    }
    for (int o = 32; o > 0; o >>= 1) lmax = fmaxf(lmax, __shfl_down(lmax, o, 64));
    if (lane == 0) s_redf[wid] = lmax;
    __syncthreads();
    if (tid == 0) {
      float m = s_redf[0];
      for (int w = 1; w < NWAVES; ++w) m = fmaxf(m, s_redf[w]);
      s_m = m;
    }
    __syncthreads();
    const float m = s_m;

    double zacc = 0.0;
    u64 best = 0;
    const u32 kc0 = s_kcat0, kc1 = s_kcat1;
    for (int i = tid; i < NW; i += NTHREADS) {
      float li = s_logit[i];
      float ex = (float)exp((double)(li - m));
      zacc += (double)ex;
      u32 ba, bb;
      tf2x32(kc0, kc1, 0u, (u32)i, &ba, &bb);
      float u = unif01(ba ^ bb);
      if (u == 0.0f) u = 1.17549435e-38f;
      float t1 = (float)log((double)u);
      float t2 = (float)log((double)(-t1));
      float g = -t2;
      float sv = g + li;
      u64 key = ((u64)fkey(sv) << 32) | (u32)(NW - 1 - i);
      if (key > best) best = key;
    }
    for (int o = 32; o > 0; o >>= 1) {
      u64 w = __shfl_down(best, o, 64);
      if (w > best) best = w;
      zacc += __shfl_down(zacc, o, 64);
    }
    if (lane == 0) { s_redu[wid] = best; s_redd[wid] = zacc; }
    __syncthreads();
    if (tid == 0) {
      u64 b = s_redu[0]; double z = s_redd[0];
      for (int w = 1; w < NWAVES; ++w) {
        if (s_redu[w] > b) b = s_redu[w];
        z += s_redd[w];
      }
      s_np = NW - 1 - (int)(b & 0xFFFFFFFFu);
      s_Z = (float)z;
    }
    __syncthreads();
    const int np = s_np;

    for (int j = tid; j < NW - 1; j += NTHREADS) {
      int a = (j < np) ? s_perm[j + (j >= pos)]
                       : ((j == np) ? tm : s_perm[(j - 1) + ((j - 1) >= pos)]);
      int j1 = j + 1;
      int b = (j1 < np) ? s_perm[j1 + (j1 >= pos)]
                        : ((j1 == np) ? tm : s_perm[(j1 - 1) + ((j1 - 1) >= pos)]);
      s_gath[j] = bigram[(u64)a * NW + b];
    }
    __syncthreads();

    if (tid == 0) {
      float S = 0.0f;
      for (int j = 0; j < NW - 1; ++j) S += s_gath[j];
      int s0 = (0 < np) ? s_perm[(0 >= pos) ? 1 : 0] : tm;
      int sl = ((NW - 1) == np) ? tm : s_perm[(NW - 2) + ((NW - 2) >= pos)];
      S = S + startv[s0];
      S = S + endv[sl];
      float dw = S - s_w;
      float e1 = (float)exp((double)dw);
      float en = (float)exp((double)(s_logit[np] - m));
      float eo = (float)exp((double)(s_logit[pos] - m));
      float pn = en / s_Z;
      float po = eo / s_Z;
      float acc = e1 * pn;
      acc = acc / po;
      acc = fminf(1.0f, acc);
      u32 ua, ub;
      tf2x32(s_ku0, s_ku1, 0u, 0u, &ua, &ub);
      float u = unif01(ua ^ ub);
      int accept = (acc > u) ? 1 : 0;
      s_acc = accept;
      if (accept) s_w = S;
    }
    __syncthreads();

    int stash[4];
    if (s_acc) {
      for (int k = 0; k < 4; ++k) {
        int i = tid + k * NTHREADS;
        stash[k] = (i < np) ? s_perm[i + (i >= pos)]
                            : ((i == np) ? tm : s_perm[(i - 1) + ((i - 1) >= pos)]);
      }
    }
    __syncthreads();
    if (s_acc) {
      for (int k = 0; k < 4; ++k) {
        int i = tid + k * NTHREADS;
        s_perm[i] = stash[k];
      }
    }
    __syncthreads();

    if (((t + 1) % 10) == 9) {
      int row = (t - 8) / 10;
      for (int i = tid; i < NW; i += NTHREADS) out[(u64)row * NW + i] = s_perm[i];
    }
    __syncthreads();
  }
}

extern "C" void kernel_launch(void* const* d_in, const int* in_sizes, int n_in,
                              void* d_out, int out_size, void* d_ws, size_t ws_size,
                              hipStream_t stream) {
  const float* bigram = (const float*)d_in[1];
  const float* startv = (const float*)d_in[2];
  const float* endv   = (const float*)d_in[3];
  int* out = (int*)d_out;

  const size_t needT = (size_t)NW * NW * sizeof(float);        // 64 MB
  const size_t needG = (size_t)NSTEPS * NW * sizeof(float);    // ~41.9 MB
  const size_t needP = (size_t)NSTEPS * (sizeof(int) + sizeof(float));

  if (ws_size >= needT + needG + needP) {
    float* bigT = (float*)d_ws;
    float* gumb = (float*)((char*)d_ws + needT);
    int* posArr = (int*)((char*)d_ws + needT + needG);
    float* uArr = (float*)((char*)d_ws + needT + needG + (size_t)NSTEPS * sizeof(int));
    hipLaunchKernelGGL(transpose_k, dim3(NW / TT, NW / TT), dim3(TT, 8), 0, stream,
                       bigram, bigT);
    long long ng = (long long)NSTEPS * NW;
    hipLaunchKernelGGL(gumbel_k, dim3((unsigned)((ng + 255) / 256)), dim3(256), 0, stream,
                       gumb);
    hipLaunchKernelGGL(posu_k, dim3((NSTEPS + 255) / 256), dim3(256), 0, stream,
                       posArr, uArr);
    hipLaunchKernelGGL(mcmc_fast11, dim3(1), dim3(NTHREADS), 0, stream,
                       bigram, bigT, gumb, posArr, uArr, startv, endv, out);
  } else {
    hipLaunchKernelGGL(mcmc_kernel, dim3(1), dim3(NTHREADS), 0, stream,
                       bigram, startv, endv, out);
  }
}